// Round 3
// baseline (1770.075 us; speedup 1.0000x reference)
//
#include <hip/hip_runtime.h>
#include <hip/hip_bf16.h>
#include <math.h>

#define N_NODES 100000
#define N_EDGES 3200000
#define F_IN    1024
#define HID     16
#define N_CLS   40

// ---- bucketing: 256 dst-nodes per bucket, fixed-capacity slices in etmp
#define BK_SHIFT 8
#define BK_NODES 256
#define NBUK     ((N_NODES + BK_NODES - 1) / BK_NODES)   // 391
#define BCAP     10240                                    // max bucket edges (mean 8186, +22 sigma)
#define EPB      16384                                    // edges per binA block
#define NBLK_A   ((N_EDGES + EPB - 1) / EPB)              // 196

typedef __attribute__((ext_vector_type(8))) short short8;
typedef __attribute__((ext_vector_type(4))) float floatx4;

// ---------------- Wt build: Wt[c][k] bf16, c in [0,48) = [W1[0] | W1[1] | root1]
__global__ void wtrans_k(const float* __restrict__ W1, const float* __restrict__ root1,
                         __hip_bfloat16* __restrict__ Wt) {
    int id = blockIdx.x * 256 + threadIdx.x;
    if (id >= 48 * 1024) return;
    int k = id & 1023, c = id >> 10;
    float v = (c < 16) ? W1[k * HID + c]
            : (c < 32) ? W1[(size_t)F_IN * HID + k * HID + (c - 16)]
                       : root1[k * HID + (c - 32)];
    Wt[(size_t)c * 1024 + k] = __float2bfloat16(v);
}

// ---------------- GEMM1 via MFMA. Outputs: y01b (N,16) bf16x2 packed (y0,y1), xr (N,16) fp32
__global__ __launch_bounds__(256) void gemm1_mfma(const float* __restrict__ x,
                                                  const __hip_bfloat16* __restrict__ Wt,
                                                  __hip_bfloat162* __restrict__ y01b,
                                                  float* __restrict__ xr)
{
    int wid = (blockIdx.x * 256 + threadIdx.x) >> 6;
    int lane = threadIdx.x & 63;
    int rowbase = wid * 16;
    if (rowbase >= N_NODES) return;
    int r = lane & 15, quad = lane >> 4;

    const float* xp = x + (size_t)(rowbase + r) * F_IN + quad * 8;
    const short* w0 = (const short*)Wt + r * 1024 + quad * 8;
    const short* w1 = w0 + 16 * 1024;
    const short* w2 = w0 + 32 * 1024;

    floatx4 acc0 = {0.f, 0.f, 0.f, 0.f};
    floatx4 acc1 = acc0, acc2 = acc0;

#pragma unroll 4
    for (int k = 0; k < F_IN; k += 32) {
        float4 a0 = *(const float4*)(xp + k);
        float4 a1 = *(const float4*)(xp + k + 4);
        union { short8 v; __hip_bfloat162 h[4]; } af;
        af.h[0] = __float22bfloat162_rn(make_float2(a0.x, a0.y));
        af.h[1] = __float22bfloat162_rn(make_float2(a0.z, a0.w));
        af.h[2] = __float22bfloat162_rn(make_float2(a1.x, a1.y));
        af.h[3] = __float22bfloat162_rn(make_float2(a1.z, a1.w));
        short8 b0 = *(const short8*)(w0 + k);
        short8 b1 = *(const short8*)(w1 + k);
        short8 b2 = *(const short8*)(w2 + k);
        acc0 = __builtin_amdgcn_mfma_f32_16x16x32_bf16(af.v, b0, acc0, 0, 0, 0);
        acc1 = __builtin_amdgcn_mfma_f32_16x16x32_bf16(af.v, b1, acc1, 0, 0, 0);
        acc2 = __builtin_amdgcn_mfma_f32_16x16x32_bf16(af.v, b2, acc2, 0, 0, 0);
    }
    int row0 = rowbase + quad * 4;
#pragma unroll
    for (int g = 0; g < 4; ++g) {
        size_t rr = (size_t)(row0 + g);
        y01b[rr * 16 + r] = __float22bfloat162_rn(make_float2(acc0[g], acc1[g]));
        xr[rr * 16 + r]   = acc2[g];
    }
}

// ---------------- Pass A: partition edges into 391 fixed-capacity dst-buckets.
// Record: [p:f32 | dstrel:8b | src:17b]. Runs of ~42 records (~340B) amortize lines.
__global__ __launch_bounds__(256) void binA_k(const int* __restrict__ ei,
                                              const float* __restrict__ eattr,
                                              int* __restrict__ bcur,
                                              unsigned long long* __restrict__ etmp) {
    __shared__ int hist[NBUK];   // phase1: counts; phase2+: absolute append cursors
    int t = threadIdx.x;
    int e0 = blockIdx.x * EPB;
    int cnt = N_EDGES - e0; if (cnt > EPB) cnt = EPB;
    for (int b = t; b < NBUK; b += 256) hist[b] = 0;
    __syncthreads();
    const int* dstp = ei + N_EDGES + e0;
    for (int i = t; i < cnt; i += 256)
        atomicAdd(&hist[dstp[i] >> BK_SHIFT], 1);
    __syncthreads();
    for (int b = t; b < NBUK; b += 256) {
        int h = hist[b];
        hist[b] = b * BCAP + (h ? atomicAdd(&bcur[b], h) : 0);
    }
    __syncthreads();
    const int* srcp = ei + e0;
    const float* pp = eattr + e0;
    for (int i = t; i < cnt; i += 256) {
        int d = dstp[i];                       // L2-hot (read in phase 1)
        int bkt = d >> BK_SHIFT;
        int pos = atomicAdd(&hist[bkt], 1);
        unsigned w0 = (unsigned)srcp[i] | ((unsigned)(d & (BK_NODES - 1)) << 17);
        etmp[pos] = ((unsigned long long)__float_as_uint(pp[i]) << 32) | w0;
    }
}

// ---------------- Fused layer-1 aggregate + ELU: one block per bucket,
// LDS accumulation (stride 17 to spread random dstrel across banks), then finalize.
__global__ __launch_bounds__(512) void bagg1_k(const __hip_bfloat162* __restrict__ y01b,
                                               const float* __restrict__ xr,
                                               const float* __restrict__ b1,
                                               const int* __restrict__ bcur,
                                               const unsigned long long* __restrict__ etmp,
                                               float* __restrict__ x1out,
                                               __hip_bfloat16* __restrict__ x1b) {
    __shared__ float sacc[BK_NODES * 17];
    __shared__ int sdeg[BK_NODES];
    int t = threadIdx.x;
    for (int i = t; i < BK_NODES * 17; i += 512) sacc[i] = 0.f;
    if (t < BK_NODES) sdeg[t] = 0;
    __syncthreads();
    int b = blockIdx.x;
    int cnt = bcur[b]; if (cnt > BCAP) cnt = BCAP;
    const unsigned long long* ep = etmp + (size_t)b * BCAP;
    int q = t & 3;
    for (int i = (t >> 2); i < cnt; i += 128) {
        unsigned long long rv = __builtin_nontemporal_load(ep + i);
        unsigned rx = (unsigned)rv;
        float p = __uint_as_float((unsigned)(rv >> 32));
        int src = rx & 0x1FFFF;
        int dr  = (rx >> 17) & (BK_NODES - 1);
        union { uint4 u; __hip_bfloat162 h[4]; } g;
        g.u = *(const uint4*)(y01b + (size_t)src * 16 + q * 4);
        float* ap = sacc + dr * 17 + q * 4;
#pragma unroll
        for (int j = 0; j < 4; ++j)
            atomicAdd(&ap[j], (1.f - p) * __low2float(g.h[j]) + p * __high2float(g.h[j]));
        if (q == 0) atomicAdd(&sdeg[dr], 1);
    }
    __syncthreads();
    if (t < BK_NODES) {
        int node = b * BK_NODES + t;
        if (node < N_NODES) {
            float invc = 1.f / fmaxf((float)sdeg[t], 1.f);
            const float* ap = sacc + t * 17;
#pragma unroll
            for (int f4 = 0; f4 < 4; ++f4) {
                float4 xrv = *(const float4*)(xr + (size_t)node * 16 + f4 * 4);
                float4 b1v = *(const float4*)(b1 + f4 * 4);
                float4 o;
                union { ushort4 s; __hip_bfloat16 h[4]; } ob;
                float z;
                z = ap[f4*4+0] * invc + xrv.x + b1v.x; o.x = z > 0.f ? z : expm1f(z); ob.h[0] = __float2bfloat16(o.x);
                z = ap[f4*4+1] * invc + xrv.y + b1v.y; o.y = z > 0.f ? z : expm1f(z); ob.h[1] = __float2bfloat16(o.y);
                z = ap[f4*4+2] * invc + xrv.z + b1v.z; o.z = z > 0.f ? z : expm1f(z); ob.h[2] = __float2bfloat16(o.z);
                z = ap[f4*4+3] * invc + xrv.w + b1v.w; o.w = z > 0.f ? z : expm1f(z); ob.h[3] = __float2bfloat16(o.w);
                *(float4*)(x1out + (size_t)node * 16 + f4 * 4) = o;
                *(ushort4*)((unsigned short*)x1b + (size_t)node * 16 + f4 * 4) = ob.s;
            }
        }
    }
}

// ---------------- Fused layer-2 aggregate + 16->40 matmul + log_softmax.
// LDS u/v at stride 35 (3*dr mod 32 spreads banks); weights staged in LDS.
__global__ __launch_bounds__(512) void bagg2_k(const __hip_bfloat16* __restrict__ x1b,
                                               const float* __restrict__ x1,
                                               const int* __restrict__ bcur,
                                               const unsigned long long* __restrict__ etmp,
                                               const float* __restrict__ W2,
                                               const float* __restrict__ root2,
                                               const float* __restrict__ b2,
                                               float* __restrict__ out0) {
    __shared__ float suv[BK_NODES * 35];   // u at dr*35+f, v at dr*35+16+f
    __shared__ float w2s[2 * HID * N_CLS];
    __shared__ float r2s[HID * N_CLS];
    __shared__ float b2s[N_CLS];
    __shared__ int sdeg[BK_NODES];
    int t = threadIdx.x;
    for (int i = t; i < BK_NODES * 35; i += 512) suv[i] = 0.f;
    if (t < BK_NODES) sdeg[t] = 0;
    for (int i = t; i < 2 * HID * N_CLS; i += 512) w2s[i] = W2[i];
    for (int i = t; i < HID * N_CLS; i += 512) r2s[i] = root2[i];
    if (t < N_CLS) b2s[t] = b2[t];
    __syncthreads();
    int b = blockIdx.x;
    int cnt = bcur[b]; if (cnt > BCAP) cnt = BCAP;
    const unsigned long long* ep = etmp + (size_t)b * BCAP;
    int q = t & 3;
    for (int i = (t >> 2); i < cnt; i += 128) {
        unsigned long long rv = __builtin_nontemporal_load(ep + i);
        unsigned rx = (unsigned)rv;
        float p = __uint_as_float((unsigned)(rv >> 32));
        int src = rx & 0x1FFFF;
        int dr  = (rx >> 17) & (BK_NODES - 1);
        union { uint2 u2; __hip_bfloat162 h[2]; } g;
        g.u2 = *(const uint2*)((const unsigned short*)x1b + (size_t)src * 16 + q * 4);
        float a0 = __low2float(g.h[0]), a1 = __high2float(g.h[0]);
        float a2 = __low2float(g.h[1]), a3 = __high2float(g.h[1]);
        float* up = suv + dr * 35 + q * 4;
        atomicAdd(&up[0], a0);       atomicAdd(&up[1], a1);
        atomicAdd(&up[2], a2);       atomicAdd(&up[3], a3);
        atomicAdd(&up[16], p * a0);  atomicAdd(&up[17], p * a1);
        atomicAdd(&up[18], p * a2);  atomicAdd(&up[19], p * a3);
        if (q == 0) atomicAdd(&sdeg[dr], 1);
    }
    __syncthreads();
    int wid = t >> 6, lane = t & 63;
    int node0 = b * BK_NODES;
    for (int n = wid; n < BK_NODES; n += 8) {
        int node = node0 + n;
        if (node >= N_NODES) break;          // wave-uniform
        float invc = 1.f / fmaxf((float)sdeg[n], 1.f);
        int c = lane;
        float val = 0.f;
        if (c < N_CLS) {
            float s1 = 0.f, s2 = 0.f;
#pragma unroll
            for (int f = 0; f < HID; ++f) {
                float u = suv[n * 35 + f], v = suv[n * 35 + 16 + f];
                float xf = x1[(size_t)node * 16 + f];
                s1 += (u - v) * w2s[f * N_CLS + c] + v * w2s[HID * N_CLS + f * N_CLS + c];
                s2 += xf * r2s[f * N_CLS + c];
            }
            val = s1 * invc + s2 + b2s[c];
        }
        float m = (c < N_CLS) ? val : -INFINITY;
#pragma unroll
        for (int o = 32; o; o >>= 1) m = fmaxf(m, __shfl_xor(m, o));
        float e = (c < N_CLS) ? expf(val - m) : 0.f;
        float ss = e;
#pragma unroll
        for (int o = 32; o; o >>= 1) ss += __shfl_xor(ss, o);
        if (c < N_CLS) out0[(size_t)node * N_CLS + c] = val - m - logf(ss);
    }
}

extern "C" void kernel_launch(void* const* d_in, const int* in_sizes, int n_in,
                              void* d_out, int out_size, void* d_ws, size_t ws_size,
                              hipStream_t stream) {
    const float* x     = (const float*)d_in[0];
    const int*   ei    = (const int*)d_in[1];
    const float* eattr = (const float*)d_in[2];
    const float* W1    = (const float*)d_in[3];
    const float* root1 = (const float*)d_in[4];
    const float* b1    = (const float*)d_in[5];
    const float* W2    = (const float*)d_in[6];
    const float* root2 = (const float*)d_in[7];
    const float* b2    = (const float*)d_in[8];

    float* out0  = (float*)d_out;                            // (100000,40)
    float* x1out = (float*)d_out + (size_t)N_NODES * N_CLS;  // (100000,16)

    char* w = (char*)d_ws;
    float* xr             = (float*)w;           w += (size_t)N_NODES * 16 * 4;  // 6.4 MB
    __hip_bfloat162* y01b = (__hip_bfloat162*)w; w += (size_t)N_NODES * 16 * 4;  // 6.4 MB
    __hip_bfloat16* x1b   = (__hip_bfloat16*)w;  w += (size_t)N_NODES * 16 * 2;  // 3.2 MB
    __hip_bfloat16* Wt    = (__hip_bfloat16*)w;  w += 48 * 1024 * 2;             // 96 KB
    int* bcur             = (int*)w;             w += 2048;                      // 391 used
    unsigned long long* etmp = (unsigned long long*)w;
    w += (size_t)NBUK * BCAP * 8;                                                // 32 MB

    (void)hipMemsetAsync(bcur, 0, NBUK * sizeof(int), stream);
    wtrans_k<<<(48 * 1024 + 255) / 256, 256, 0, stream>>>(W1, root1, Wt);
    gemm1_mfma<<<(N_NODES / 16 + 3) / 4, 256, 0, stream>>>(x, Wt, y01b, xr);
    binA_k<<<NBLK_A, 256, 0, stream>>>(ei, eattr, bcur, etmp);
    bagg1_k<<<NBUK, 512, 0, stream>>>(y01b, xr, b1, bcur, etmp, x1out, x1b);
    bagg2_k<<<NBUK, 512, 0, stream>>>(x1b, x1out, bcur, etmp, W2, root2, b2, out0);
}

// Round 4
// 991.279 us; speedup vs baseline: 1.7856x; 1.7856x over previous
//
#include <hip/hip_runtime.h>
#include <hip/hip_bf16.h>
#include <math.h>

#define N_NODES 100000
#define N_EDGES 3200000
#define F_IN    1024
#define HID     16
#define N_CLS   40

// ---- bucketing: 128 dst-nodes per bucket; etmp slices are CSR-aligned
//      [rowptr[b*128], rowptr[(b+1)*128]) so no fixed-capacity waste.
#define BK_SHIFT 7
#define BKN      128
#define NBUK     ((N_NODES + BKN - 1) / BKN)             // 782
#define EPB      16384                                    // edges per binA block
#define NBLK_A   ((N_EDGES + EPB - 1) / EPB)              // 196

typedef __attribute__((ext_vector_type(8))) short short8;
typedef __attribute__((ext_vector_type(4))) float floatx4;

// ---------------- Wt build: Wt[c][k] bf16, c in [0,48) = [W1[0] | W1[1] | root1]
__global__ void wtrans_k(const float* __restrict__ W1, const float* __restrict__ root1,
                         __hip_bfloat16* __restrict__ Wt) {
    int id = blockIdx.x * 256 + threadIdx.x;
    if (id >= 48 * 1024) return;
    int k = id & 1023, c = id >> 10;
    float v = (c < 16) ? W1[k * HID + c]
            : (c < 32) ? W1[(size_t)F_IN * HID + k * HID + (c - 16)]
                       : root1[k * HID + (c - 32)];
    Wt[(size_t)c * 1024 + k] = __float2bfloat16(v);
}

// ---------------- GEMM1 via MFMA. Outputs: y01b (N,16) bf16x2 packed (y0,y1), xr (N,16) fp32
__global__ __launch_bounds__(256) void gemm1_mfma(const float* __restrict__ x,
                                                  const __hip_bfloat16* __restrict__ Wt,
                                                  __hip_bfloat162* __restrict__ y01b,
                                                  float* __restrict__ xr)
{
    int wid = (blockIdx.x * 256 + threadIdx.x) >> 6;
    int lane = threadIdx.x & 63;
    int rowbase = wid * 16;
    if (rowbase >= N_NODES) return;
    int r = lane & 15, quad = lane >> 4;

    const float* xp = x + (size_t)(rowbase + r) * F_IN + quad * 8;
    const short* w0 = (const short*)Wt + r * 1024 + quad * 8;
    const short* w1 = w0 + 16 * 1024;
    const short* w2 = w0 + 32 * 1024;

    floatx4 acc0 = {0.f, 0.f, 0.f, 0.f};
    floatx4 acc1 = acc0, acc2 = acc0;

#pragma unroll 4
    for (int k = 0; k < F_IN; k += 32) {
        float4 a0 = *(const float4*)(xp + k);
        float4 a1 = *(const float4*)(xp + k + 4);
        union { short8 v; __hip_bfloat162 h[4]; } af;
        af.h[0] = __float22bfloat162_rn(make_float2(a0.x, a0.y));
        af.h[1] = __float22bfloat162_rn(make_float2(a0.z, a0.w));
        af.h[2] = __float22bfloat162_rn(make_float2(a1.x, a1.y));
        af.h[3] = __float22bfloat162_rn(make_float2(a1.z, a1.w));
        short8 b0 = *(const short8*)(w0 + k);
        short8 b1 = *(const short8*)(w1 + k);
        short8 b2 = *(const short8*)(w2 + k);
        acc0 = __builtin_amdgcn_mfma_f32_16x16x32_bf16(af.v, b0, acc0, 0, 0, 0);
        acc1 = __builtin_amdgcn_mfma_f32_16x16x32_bf16(af.v, b1, acc1, 0, 0, 0);
        acc2 = __builtin_amdgcn_mfma_f32_16x16x32_bf16(af.v, b2, acc2, 0, 0, 0);
    }
    int row0 = rowbase + quad * 4;
#pragma unroll
    for (int g = 0; g < 4; ++g) {
        size_t rr = (size_t)(row0 + g);
        y01b[rr * 16 + r] = __float22bfloat162_rn(make_float2(acc0[g], acc1[g]));
        xr[rr * 16 + r]   = acc2[g];
    }
}

// ---------------- CSR build (int4 reads)
__global__ void hist_k(const int* __restrict__ dst, int* __restrict__ counts) {
    int t = blockIdx.x * 256 + threadIdx.x;          // N_EDGES/4 threads exact
    int4 d = ((const int4*)dst)[t];
    atomicAdd(&counts[d.x], 1);
    atomicAdd(&counts[d.y], 1);
    atomicAdd(&counts[d.z], 1);
    atomicAdd(&counts[d.w], 1);
}

__global__ __launch_bounds__(256) void scan1_k(const int* __restrict__ counts,
                                               int* __restrict__ rowptr,
                                               int* __restrict__ partials) {
    __shared__ int sdata[256];
    int t = threadIdx.x;
    int base = blockIdx.x * 1024 + t * 4;
    int v[4];
#pragma unroll
    for (int i = 0; i < 4; ++i) v[i] = (base + i < N_NODES) ? counts[base + i] : 0;
    int tsum = v[0] + v[1] + v[2] + v[3];
    sdata[t] = tsum;
    __syncthreads();
    for (int o = 1; o < 256; o <<= 1) {
        int xv = (t >= o) ? sdata[t - o] : 0;
        __syncthreads();
        sdata[t] += xv;
        __syncthreads();
    }
    int run = sdata[t] - tsum;
#pragma unroll
    for (int i = 0; i < 4; ++i) {
        if (base + i < N_NODES) rowptr[base + i] = run;
        run += v[i];
    }
    if (t == 255) partials[blockIdx.x] = sdata[255];
}

__global__ void scan2_k(int* __restrict__ partials, int nb) {
    __shared__ int s[128];
    int t = threadIdx.x;
    int v = (t < nb) ? partials[t] : 0;
    s[t] = v;
    __syncthreads();
    for (int o = 1; o < 128; o <<= 1) {
        int xv = (t >= o) ? s[t - o] : 0;
        __syncthreads();
        s[t] += xv;
        __syncthreads();
    }
    if (t < nb) partials[t] = s[t] - v;
}

__global__ void scan3_k(int* __restrict__ rowptr, const int* __restrict__ partials) {
    int i = blockIdx.x * 256 + threadIdx.x;
    if (i < N_NODES) rowptr[i] += partials[i >> 10];
    if (i == N_NODES) rowptr[N_NODES] = N_EDGES;
}

// ---------------- per-bucket append cursor = rowptr at bucket start
__global__ void binit_k(const int* __restrict__ rowptr, int* __restrict__ bcur) {
    int b = blockIdx.x * 256 + threadIdx.x;
    if (b < NBUK) bcur[b] = rowptr[b * BKN];
}

// ---------------- Pass A: partition edges into 782 dst-buckets (CSR-aligned slices).
// Record: [p:f32 | dstrel:7b | src:17b]. Runs ~21 records (~170B) amortize lines.
__global__ __launch_bounds__(256) void binA_k(const int* __restrict__ ei,
                                              const float* __restrict__ eattr,
                                              int* __restrict__ bcur,
                                              unsigned long long* __restrict__ etmp) {
    __shared__ int hist[NBUK];   // phase1: counts; phase2+: absolute append cursors
    int t = threadIdx.x;
    int e0 = blockIdx.x * EPB;
    int cnt = N_EDGES - e0; if (cnt > EPB) cnt = EPB;
    for (int b = t; b < NBUK; b += 256) hist[b] = 0;
    __syncthreads();
    const int* dstp = ei + N_EDGES + e0;
    for (int i = t; i < cnt; i += 256)
        atomicAdd(&hist[dstp[i] >> BK_SHIFT], 1);
    __syncthreads();
    for (int b = t; b < NBUK; b += 256) {
        int h = hist[b];
        hist[b] = h ? atomicAdd(&bcur[b], h) : 0;   // reserve this block's run (absolute)
    }
    __syncthreads();
    const int* srcp = ei + e0;
    const float* pp = eattr + e0;
    for (int i = t; i < cnt; i += 256) {
        int d = dstp[i];                       // L2-hot (read in phase 1)
        int bkt = d >> BK_SHIFT;
        int pos = atomicAdd(&hist[bkt], 1);
        unsigned w0 = (unsigned)srcp[i] | ((unsigned)(d & (BKN - 1)) << 17);
        etmp[pos] = ((unsigned long long)__float_as_uint(pp[i]) << 32) | w0;
    }
}

// ---------------- Fused binB + layer-1 aggregate + ELU. One block per 128-node bucket.
// Phase 1: exact-CSR scatter etmp->erec via native LDS *int* cursors (1 atomic/edge;
//          writes land in a ~32KB L2-hot window). Phase 2: wave-per-node shuffle
//          reduction reading the just-written (L2-hot) erec. No f32 atomics anywhere.
__global__ __launch_bounds__(512) void bagg1_k(const __hip_bfloat162* __restrict__ y01b,
                                               const float* __restrict__ xr,
                                               const float* __restrict__ b1,
                                               const int* __restrict__ rowptr,
                                               const unsigned long long* __restrict__ etmp,
                                               uint2* __restrict__ erec,
                                               float* __restrict__ x1out,
                                               __hip_bfloat16* __restrict__ x1b) {
    __shared__ int srp[BKN + 1];
    __shared__ int scur[BKN];
    int b = blockIdx.x, t = threadIdx.x;
    int n0 = b * BKN;
    int nn = N_NODES - n0; if (nn > BKN) nn = BKN;
    if (t <= nn) {
        int r = rowptr[n0 + t];
        srp[t] = r;
        if (t < nn) scur[t] = r;
    }
    __syncthreads();
    int s = srp[0], e = srp[nn];
    // phase 1: scatter to exact CSR slots
    for (int i = s + t; i < e; i += 512) {
        unsigned long long rv = __builtin_nontemporal_load(etmp + i);
        unsigned rx = (unsigned)rv;
        int dr = (rx >> 17) & (BKN - 1);
        int pos = atomicAdd(&scur[dr], 1);
        erec[pos] = make_uint2(rx & 0x1FFFFu, (unsigned)(rv >> 32));
    }
    __syncthreads();
    // phase 2: wave-per-node pull + ELU (erec L2/L1-hot)
    int wid = t >> 6, lane = t & 63;
    int q = lane & 3, slot = lane >> 2;
    for (int n = wid; n < nn; n += 8) {
        int node = n0 + n;
        int start = srp[n], end = srp[n + 1];
        float acc[4] = {0.f, 0.f, 0.f, 0.f};
#pragma unroll 2
        for (int i = start + slot; i < end; i += 16) {
            uint2 rec = erec[i];
            float p = __uint_as_float(rec.y);
            union { uint4 u; __hip_bfloat162 h[4]; } g;
            g.u = *(const uint4*)(y01b + (size_t)rec.x * 16 + q * 4);
#pragma unroll
            for (int j = 0; j < 4; ++j)
                acc[j] += (1.f - p) * __low2float(g.h[j]) + p * __high2float(g.h[j]);
        }
#pragma unroll
        for (int off = 4; off < 64; off <<= 1)
#pragma unroll
            for (int j = 0; j < 4; ++j) acc[j] += __shfl_xor(acc[j], off);
        if (slot == 0) {
            float invc = 1.f / fmaxf((float)(end - start), 1.f);
            float4 xrv = *(const float4*)(xr + (size_t)node * 16 + q * 4);
            float4 b1v = *(const float4*)(b1 + q * 4);
            float4 o;
            union { ushort4 sv; __hip_bfloat16 h[4]; } ob;
            float z;
            z = acc[0] * invc + xrv.x + b1v.x; o.x = z > 0.f ? z : expm1f(z); ob.h[0] = __float2bfloat16(o.x);
            z = acc[1] * invc + xrv.y + b1v.y; o.y = z > 0.f ? z : expm1f(z); ob.h[1] = __float2bfloat16(o.y);
            z = acc[2] * invc + xrv.z + b1v.z; o.z = z > 0.f ? z : expm1f(z); ob.h[2] = __float2bfloat16(o.z);
            z = acc[3] * invc + xrv.w + b1v.w; o.w = z > 0.f ? z : expm1f(z); ob.h[3] = __float2bfloat16(o.w);
            *(float4*)(x1out + (size_t)node * 16 + q * 4) = o;
            *(ushort4*)((unsigned short*)x1b + (size_t)node * 16 + q * 4) = ob.sv;
        }
    }
}

// ---------------- Layer-2 pull + 16->40 matmul + log_softmax. 4 lanes/edge x 8B gather.
__global__ __launch_bounds__(256) void agg2f_k(const __hip_bfloat16* __restrict__ x1b,
                                               const float* __restrict__ x1,
                                               const int* __restrict__ rowptr,
                                               const uint2* __restrict__ erec,
                                               const float* __restrict__ W2,
                                               const float* __restrict__ root2,
                                               const float* __restrict__ b2,
                                               float* __restrict__ out0) {
    __shared__ float Us[4][16], Vs[4][16], Xs[4][16];
    int w = threadIdx.x >> 6;
    int node = (blockIdx.x * 256 + threadIdx.x) >> 6;
    int lane = threadIdx.x & 63;
    if (node >= N_NODES) return;   // grid exact
    int q = lane & 3, slot = lane >> 2;
    int start = rowptr[node], end = rowptr[node + 1];
    float u[4] = {0.f, 0.f, 0.f, 0.f}, v[4] = {0.f, 0.f, 0.f, 0.f};
#pragma unroll 2
    for (int i = start + slot; i < end; i += 16) {
        uint2 rec = erec[i];
        float p = __uint_as_float(rec.y);
        union { uint2 u2; __hip_bfloat162 h[2]; } g;
        g.u2 = *(const uint2*)((const unsigned short*)x1b + (size_t)rec.x * 16 + q * 4);
        float a0 = __low2float(g.h[0]), a1 = __high2float(g.h[0]);
        float a2 = __low2float(g.h[1]), a3 = __high2float(g.h[1]);
        u[0] += a0; u[1] += a1; u[2] += a2; u[3] += a3;
        v[0] += p * a0; v[1] += p * a1; v[2] += p * a2; v[3] += p * a3;
    }
#pragma unroll
    for (int off = 4; off < 64; off <<= 1)
#pragma unroll
        for (int j = 0; j < 4; ++j) {
            u[j] += __shfl_xor(u[j], off);
            v[j] += __shfl_xor(v[j], off);
        }
    if (slot == 0) {
        ((float4*)Us[w])[q] = make_float4(u[0], u[1], u[2], u[3]);
        ((float4*)Vs[w])[q] = make_float4(v[0], v[1], v[2], v[3]);
        ((float4*)Xs[w])[q] = *(const float4*)(x1 + (size_t)node * 16 + q * 4);
    }
    __syncthreads();
    float invc = 1.f / fmaxf((float)(end - start), 1.f);
    int c = lane;
    float val = 0.f;
    if (c < N_CLS) {
        float s1 = 0.f, s2 = 0.f;
#pragma unroll
        for (int ff = 0; ff < HID; ++ff) {
            float uu = Us[w][ff], vV = Vs[w][ff];
            s1 += (uu - vV) * W2[ff * N_CLS + c] + vV * W2[HID * N_CLS + ff * N_CLS + c];
            s2 += Xs[w][ff] * root2[ff * N_CLS + c];
        }
        val = s1 * invc + s2 + b2[c];
    }
    float m = (c < N_CLS) ? val : -INFINITY;
#pragma unroll
    for (int o = 32; o; o >>= 1) m = fmaxf(m, __shfl_xor(m, o));
    float e = (c < N_CLS) ? expf(val - m) : 0.f;
    float ss = e;
#pragma unroll
    for (int o = 32; o; o >>= 1) ss += __shfl_xor(ss, o);
    if (c < N_CLS) out0[(size_t)node * N_CLS + c] = val - m - logf(ss);
}

extern "C" void kernel_launch(void* const* d_in, const int* in_sizes, int n_in,
                              void* d_out, int out_size, void* d_ws, size_t ws_size,
                              hipStream_t stream) {
    const float* x     = (const float*)d_in[0];
    const int*   ei    = (const int*)d_in[1];
    const float* eattr = (const float*)d_in[2];
    const float* W1    = (const float*)d_in[3];
    const float* root1 = (const float*)d_in[4];
    const float* b1    = (const float*)d_in[5];
    const float* W2    = (const float*)d_in[6];
    const float* root2 = (const float*)d_in[7];
    const float* b2    = (const float*)d_in[8];

    float* out0  = (float*)d_out;                            // (100000,40)
    float* x1out = (float*)d_out + (size_t)N_NODES * N_CLS;  // (100000,16)

    char* w = (char*)d_ws;
    float* xr             = (float*)w;           w += (size_t)N_NODES * 16 * 4;  // 6.4 MB
    __hip_bfloat162* y01b = (__hip_bfloat162*)w; w += (size_t)N_NODES * 16 * 4;  // 6.4 MB
    __hip_bfloat16* x1b   = (__hip_bfloat16*)w;  w += (size_t)N_NODES * 16 * 2;  // 3.2 MB
    __hip_bfloat16* Wt    = (__hip_bfloat16*)w;  w += 48 * 1024 * 2;             // 96 KB
    int*   counts = (int*)w;   w += (size_t)N_NODES * 4;
    int*   rowptr = (int*)w;   w += (size_t)(N_NODES + 4) * 4;
    int*   parts  = (int*)w;   w += 1024;
    int*   bcur   = (int*)w;   w += 4096;                                        // 782 used
    unsigned long long* etmp = (unsigned long long*)w; w += (size_t)N_EDGES * 8; // 25.6 MB
    uint2* erec   = (uint2*)w; w += (size_t)N_EDGES * 8;                          // 25.6 MB

    const int NB_SCAN = (N_NODES + 1023) / 1024;  // 98

    (void)hipMemsetAsync(counts, 0, N_NODES * sizeof(int), stream);
    wtrans_k<<<(48 * 1024 + 255) / 256, 256, 0, stream>>>(W1, root1, Wt);
    gemm1_mfma<<<(N_NODES / 16 + 3) / 4, 256, 0, stream>>>(x, Wt, y01b, xr);
    hist_k<<<N_EDGES / 4 / 256, 256, 0, stream>>>(ei + N_EDGES, counts);
    scan1_k<<<NB_SCAN, 256, 0, stream>>>(counts, rowptr, parts);
    scan2_k<<<1, 128, 0, stream>>>(parts, NB_SCAN);
    scan3_k<<<(N_NODES + 256) / 256, 256, 0, stream>>>(rowptr, parts);
    binit_k<<<(NBUK + 255) / 256, 256, 0, stream>>>(rowptr, bcur);
    binA_k<<<NBLK_A, 256, 0, stream>>>(ei, eattr, bcur, etmp);
    bagg1_k<<<NBUK, 512, 0, stream>>>(y01b, xr, b1, rowptr, etmp, erec, x1out, x1b);
    agg2f_k<<<N_NODES * 64 / 256, 256, 0, stream>>>(x1b, x1out, rowptr, erec, W2, root2, b2, out0);
}